// Round 10
// baseline (172.263 us; speedup 1.0000x reference)
//
#include <hip/hip_runtime.h>
#include <hip/hip_bf16.h>
#include <cmath>

#define NB 64
#define NM 1024
#define NE 1024
#define NH 8
#define NHD 128
#define NMID 64
#define CELU_ALPHA 1.3f

typedef __attribute__((ext_vector_type(8))) short bf16x8;
typedef __attribute__((ext_vector_type(4))) float f32x4;

__device__ __forceinline__ float celuf(float x) {
    return x > 0.f ? x : CELU_ALPHA * expm1f(x / CELU_ALPHA);
}

__device__ __forceinline__ short f2bf(float x) {
    __hip_bfloat16 b = __float2bfloat16(x);
    return *reinterpret_cast<short*>(&b);
}

// ---------------------------------------------------------------------------
// A1: LDS-tiled fp32 GEMM partials for q/v1 pre-activations.
// grid 256 = mat(2) x kq(8) x cc(16 of 64 cols), block 256.
// ---------------------------------------------------------------------------
__global__ __launch_bounds__(256) void a1_tile(
    const float* __restrict__ h, const float* __restrict__ Wq,
    const float* __restrict__ Wv1, float* __restrict__ partA)
{
    const int t = threadIdx.x;
    const int mat = blockIdx.x >> 7;
    const int kq = (blockIdx.x >> 4) & 7;
    const int cc = (blockIdx.x & 15) * 64;
    const int kbase = kq * 128;
    const float* __restrict__ W = mat ? Wv1 : Wq;

    __shared__ float wl[128][64];
    __shared__ float hl[64][132];

#pragma unroll
    for (int u = 0; u < 8; ++u) {            // stage W tile: 128x64
        const int f = t + 256 * u;
        const int row = f >> 4, c4 = f & 15;
        *(float4*)&wl[row][c4 * 4] =
            *(const float4*)&W[(size_t)(kbase + row) * 1024 + cc + c4 * 4];
    }
#pragma unroll
    for (int u = 0; u < 8; ++u) {            // stage h tile: 64x128
        const int f = t + 256 * u;
        const int r = f >> 5, k4 = f & 31;
        *(float4*)&hl[r][k4 * 4] = *(const float4*)&h[r * 1024 + kbase + k4 * 4];
    }
    __syncthreads();

    const int r0 = (t >> 4) * 4;
    const int c0 = (t & 15) * 4;
    float acc[4][4];
#pragma unroll
    for (int i = 0; i < 4; ++i)
#pragma unroll
        for (int j = 0; j < 4; ++j) acc[i][j] = 0.f;

#pragma unroll 4
    for (int k = 0; k < 128; ++k) {
        const float4 w4 = *(const float4*)&wl[k][c0];
        const float h0 = hl[r0][k], h1 = hl[r0 + 1][k];
        const float h2 = hl[r0 + 2][k], h3 = hl[r0 + 3][k];
        acc[0][0] = fmaf(h0, w4.x, acc[0][0]); acc[0][1] = fmaf(h0, w4.y, acc[0][1]);
        acc[0][2] = fmaf(h0, w4.z, acc[0][2]); acc[0][3] = fmaf(h0, w4.w, acc[0][3]);
        acc[1][0] = fmaf(h1, w4.x, acc[1][0]); acc[1][1] = fmaf(h1, w4.y, acc[1][1]);
        acc[1][2] = fmaf(h1, w4.z, acc[1][2]); acc[1][3] = fmaf(h1, w4.w, acc[1][3]);
        acc[2][0] = fmaf(h2, w4.x, acc[2][0]); acc[2][1] = fmaf(h2, w4.y, acc[2][1]);
        acc[2][2] = fmaf(h2, w4.z, acc[2][2]); acc[2][3] = fmaf(h2, w4.w, acc[2][3]);
        acc[3][0] = fmaf(h3, w4.x, acc[3][0]); acc[3][1] = fmaf(h3, w4.y, acc[3][1]);
        acc[3][2] = fmaf(h3, w4.z, acc[3][2]); acc[3][3] = fmaf(h3, w4.w, acc[3][3]);
    }

    float* __restrict__ out = partA + (size_t)(mat * 8 + kq) * 65536;
#pragma unroll
    for (int i = 0; i < 4; ++i) {
        float4 v = {acc[i][0], acc[i][1], acc[i][2], acc[i][3]};
        *(float4*)&out[(r0 + i) * 1024 + cc + c0] = v;
    }
}

// ---------------------------------------------------------------------------
// A2B0: per-(b,h): sum partials + bias + CELU + groupnorm (ddof=1) for q & v1,
// write v1buf, build wbq_g (bf16, fragment-ready). grid 512 = (b,h).
// Wb staged coalesced in LDS (fixes strided-scatter over-fetch).
// ---------------------------------------------------------------------------
__global__ __launch_bounds__(256) void a2b0(
    const float* __restrict__ partA,
    const float* __restrict__ bq, const float* __restrict__ bv1,
    const float* __restrict__ gnw_q, const float* __restrict__ gnb_q,
    const float* __restrict__ gnw_v, const float* __restrict__ gnb_v,
    const float* __restrict__ Wb,
    float* __restrict__ v1buf, short* __restrict__ wbq_g)
{
    const int bid = blockIdx.x;
    const int b = bid >> 3, hh = bid & 7;
    const int t = threadIdx.x;
    const int mat = t >> 7;          // 0 = q, 1 = v1
    const int c = t & 127;
    const int ch = hh * 128 + c;
    const int w = t >> 6, lane = t & 63;

    __shared__ float q_lds[128];
    __shared__ float red[4][2];
    __shared__ float wb_l[128][68];  // Wb[hh] staged [i][o], pad 68

    // stage Wb[hh] coalesced: 2048 float4s
#pragma unroll
    for (int u = 0; u < 8; ++u) {
        const int f = t + 256 * u;
        const int i = f >> 4, o4 = f & 15;
        *(float4*)&wb_l[i][o4 * 4] = *(const float4*)&Wb[hh * 8192 + i * 64 + o4 * 4];
    }

    float x = mat ? bv1[ch] : bq[ch];
#pragma unroll
    for (int kq = 0; kq < 8; ++kq)
        x += partA[(size_t)(mat * 8 + kq) * 65536 + b * 1024 + ch];
    x = celuf(x);

    float s = x, s2 = x * x;
#pragma unroll
    for (int m = 32; m >= 1; m >>= 1) {
        s += __shfl_xor(s, m);
        s2 += __shfl_xor(s2, m);
    }
    if (lane == 0) { red[w][0] = s; red[w][1] = s2; }
    __syncthreads();                  // red + wb_l ready
    const float S  = red[mat * 2][0] + red[mat * 2 + 1][0];
    const float S2 = red[mat * 2][1] + red[mat * 2 + 1][1];
    const float mean = S * (1.f / 128.f);
    const float var = (S2 - 128.f * mean * mean) * (1.f / 127.f);
    const float inv = rsqrtf(var + 1e-5f);
    const float gw = mat ? gnw_v[ch] : gnw_q[ch];
    const float gb = mat ? gnb_v[ch] : gnb_q[ch];
    const float y = (x - mean) * inv * gw + gb;
    if (mat == 0) q_lds[c] = y;
    else v1buf[b * 1024 + ch] = y;
    __syncthreads();

    // build wbq_g[bid][o][i]: thread owns o = t&63, i-block (t>>6)*32
    const int o = t & 63;
    const int i0 = (t >> 6) * 32;
    union { short sv[32]; uint4 q4[4]; } u;
#pragma unroll 8
    for (int v = 0; v < 32; ++v) {
        const int i = i0 + v;
        u.sv[v] = f2bf(q_lds[i] * wb_l[i][o]);
    }
    uint4* dst = (uint4*)&wbq_g[(size_t)bid * 8192 + o * 128 + i0];
#pragma unroll
    for (int r = 0; r < 4; ++r) dst[r] = u.q4[r];
}

// ---------------------------------------------------------------------------
// B: fused flash-style streaming over K and V halves. grid 2048 = (b,h,chunk)
// wbq in LDS (XOR seg-swizzle); also emits per-chunk mask sums.
// ---------------------------------------------------------------------------
__global__ __launch_bounds__(256) void b_fused(
    const float* __restrict__ pat, const float* __restrict__ mask,
    const short* __restrict__ wbq_g,
    const float* __restrict__ bb, const float* __restrict__ Ws,
    const float* __restrict__ bs,
    float* __restrict__ pool_pt, float* __restrict__ esum_pt,
    float* __restrict__ msum_pt, float* __restrict__ av_pt)
{
    const int t = threadIdx.x;
    const int bid = blockIdx.x;
    const int b = bid >> 5;
    const int h = (bid >> 2) & 7;
    const int chunk = bid & 3;
    const int w = t >> 6;
    const int lane = t & 63;
    const int ln15 = lane & 15;
    const int lg = lane >> 4;
    const int dg = lane & 31;
    const int rwg = lane >> 5;

    __shared__ short wbq_lds[64 * 128];
    __shared__ float mask_lds[256];
    __shared__ float e_lds[4][16];
    __shared__ float att_red[4][128];
    __shared__ float pool_red[4][64];
    __shared__ float esum_red[4];
    __shared__ float msum_red[4];

    const float mk0 = mask[b * 1024 + chunk * 256 + t];
    mask_lds[t] = mk0;
    {
        float msp = mk0;
#pragma unroll
        for (int m = 32; m >= 1; m >>= 1) msp += __shfl_xor(msp, m);
        if (lane == 0) msum_red[w] = msp;
    }

    // stage wbq (16 KB) with seg-swizzle
    {
        const short* __restrict__ wb = wbq_g + (size_t)(bid >> 2) * 8192;
#pragma unroll
        for (int u = 0; u < 4; ++u) {
            const int f = t + 256 * u;          // 1024 segs of 16 B
            const int row = f >> 4, seg = f & 15;
            const int sseg = seg ^ (row & 7);
            *(uint4*)((char*)wbq_lds + row * 256 + sseg * 16) =
                *(const uint4*)(wb + row * 128 + seg * 8);
        }
    }

    float wsr[4], bbr[4];
#pragma unroll
    for (int nt = 0; nt < 4; ++nt) {
        wsr[nt] = Ws[h * 64 + nt * 16 + ln15];
        bbr[nt] = bb[h * 64 + nt * 16 + ln15];
    }
    const float bsh = bs[h];
    float pool_part[4] = {0.f, 0.f, 0.f, 0.f};
    float esum_part = 0.f;
    float4 a4 = {0.f, 0.f, 0.f, 0.f};

    const float* __restrict__ patk = pat + (size_t)b * NM * 2048 + h * 128;
    const float* __restrict__ patv = patk + 1024;

    __syncthreads();   // mask_lds + wbq_lds ready

    for (int it = 0; it < 4; ++it) {
        const int ml0 = (w * 4 + it) * 16;       // row within chunk
        const int m0 = chunk * 256 + ml0;        // global row

        // ---- A loads for this tile (8 x float4 in flight) ----
        const float* __restrict__ rowp = patk + (size_t)(m0 + ln15) * 2048 + lg * 8;
        float4 ax[4], ay[4];
#pragma unroll
        for (int ks = 0; ks < 4; ++ks) {
            ax[ks] = *(const float4*)(rowp + ks * 32);
            ay[ks] = *(const float4*)(rowp + ks * 32 + 4);
        }

        // ---- cvt A to bf16 fragments ----
        bf16x8 af[4];
#pragma unroll
        for (int ks = 0; ks < 4; ++ks) {
            union { bf16x8 v; short s[8]; } u8;
            u8.s[0] = f2bf(ax[ks].x); u8.s[1] = f2bf(ax[ks].y);
            u8.s[2] = f2bf(ax[ks].z); u8.s[3] = f2bf(ax[ks].w);
            u8.s[4] = f2bf(ay[ks].x); u8.s[5] = f2bf(ay[ks].y);
            u8.s[6] = f2bf(ay[ks].z); u8.s[7] = f2bf(ay[ks].w);
            af[ks] = u8.v;
        }

        // ---- MFMA: per ks, pull 4 B-frags from LDS (swizzled) ----
        f32x4 acc[4];
#pragma unroll
        for (int nt = 0; nt < 4; ++nt) acc[nt] = (f32x4){0.f, 0.f, 0.f, 0.f};
#pragma unroll
        for (int ks = 0; ks < 4; ++ks) {
            bf16x8 bq[4];
#pragma unroll
            for (int nt = 0; nt < 4; ++nt) {
                const int row = nt * 16 + ln15;
                const int sseg = (ks * 4 + lg) ^ (ln15 & 7);
                bq[nt] = *(const bf16x8*)((const char*)wbq_lds + row * 256 + sseg * 16);
            }
#pragma unroll
            for (int nt = 0; nt < 4; ++nt)
                acc[nt] = __builtin_amdgcn_mfma_f32_16x16x32_bf16(af[ks], bq[nt], acc[nt], 0, 0, 0);
        }

        // ---- epilogue: bias+relu, score dot Ws, pool, e = exp ----
#pragma unroll
        for (int j = 0; j < 4; ++j) {
            const int ml = ml0 + lg * 4 + j;
            const float mk = mask_lds[ml];
            float sp = 0.f;
#pragma unroll
            for (int nt = 0; nt < 4; ++nt) {
                float a = acc[nt][j] + bbr[nt];
                a = fmaxf(a, 0.f);
                sp = fmaf(a, wsr[nt], sp);
                pool_part[nt] = fmaf(a, mk, pool_part[nt]);
            }
            sp += __shfl_xor(sp, 1);
            sp += __shfl_xor(sp, 2);
            sp += __shfl_xor(sp, 4);
            sp += __shfl_xor(sp, 8);
            if (ln15 == 0) {
                const float e = (mk == 0.f) ? 0.f : expf(sp + bsh);
                e_lds[w][lg * 4 + j] = e;    // wave-local (same-wave DS order)
                esum_part += e;
            }
        }

        // ---- V accumulate: inline loads, partial unroll ----
        const float* __restrict__ vrow = patv + (size_t)(m0 + rwg) * 2048 + dg * 4;
#pragma unroll 4
        for (int r = 0; r < 8; ++r) {
            const float4 v = *(const float4*)(vrow + (size_t)(2 * r) * 2048);
            const float e = e_lds[w][rwg + 2 * r];
            a4.x = fmaf(e, v.x, a4.x);
            a4.y = fmaf(e, v.y, a4.y);
            a4.z = fmaf(e, v.z, a4.z);
            a4.w = fmaf(e, v.w, a4.w);
        }
    }

    // ---- reductions ----
    a4.x += __shfl_xor(a4.x, 32);
    a4.y += __shfl_xor(a4.y, 32);
    a4.z += __shfl_xor(a4.z, 32);
    a4.w += __shfl_xor(a4.w, 32);
    if (lane < 32) *(float4*)&att_red[w][dg * 4] = a4;

#pragma unroll
    for (int nt = 0; nt < 4; ++nt) {
        float p = pool_part[nt];
        p += __shfl_xor(p, 16);
        p += __shfl_xor(p, 32);
        if (lane < 16) pool_red[w][nt * 16 + lane] = p;
    }

#pragma unroll
    for (int m = 32; m >= 1; m >>= 1) esum_part += __shfl_xor(esum_part, m);
    if (lane == 0) esum_red[w] = esum_part;
    __syncthreads();

    if (t < 128)
        av_pt[(size_t)bid * 128 + t] =
            att_red[0][t] + att_red[1][t] + att_red[2][t] + att_red[3][t];
    else if (t < 192)
        pool_pt[(size_t)bid * 64 + (t - 128)] =
            pool_red[0][t - 128] + pool_red[1][t - 128] + pool_red[2][t - 128] + pool_red[3][t - 128];
    else if (t == 192)
        esum_pt[bid] = esum_red[0] + esum_red[1] + esum_red[2] + esum_red[3];
    else if (t == 193)
        msum_pt[bid] = msum_red[0] + msum_red[1] + msum_red[2] + msum_red[3];
}

// ---------------------------------------------------------------------------
// C1 (fused finalize + GEMM): grid 256 = kq(16) x cc(16), block 256.
// kq<8: x-tile = h rows.  kq>=8 (head hh=kq-8): reconstruct att tile in LDS
// (av/esum/pool sums + Wc GEMV + sigmoid + x v1), then GEMM from LDS.
// ---------------------------------------------------------------------------
__global__ __launch_bounds__(256) void c1_fused(
    const float* __restrict__ h, const float* __restrict__ Wt,
    const float* __restrict__ pool_pt, const float* __restrict__ esum_pt,
    const float* __restrict__ msum_pt, const float* __restrict__ av_pt,
    const float* __restrict__ Wc, const float* __restrict__ bc,
    const float* __restrict__ v1, float* __restrict__ part)
{
    const int t = threadIdx.x;
    const int kq = blockIdx.x >> 4;
    const int cc = (blockIdx.x & 15) * 64;

    __shared__ float wl[128][64];     // GEMM W tile; phase0 alias: Wc[hh] as [64][128]
    __shared__ float xl[64][132];     // x tile (h rows or att rows)
    __shared__ float pool2_l[64][64];
    __shared__ float esum_l[64];
    __shared__ float msum_l[64];

    float (*wc_l)[128] = (float(*)[128])wl;

    if (kq >= 8) {
        const int hh = kq & 7;
        // stage Wc[hh] coalesced (8192 floats)
#pragma unroll
        for (int u = 0; u < 8; ++u) {
            const int f = t + 256 * u;       // float4 index
            const int o = f >> 5, d4 = f & 31;
            *(float4*)&wc_l[o][d4 * 4] = *(const float4*)&Wc[hh * 8192 + o * 128 + d4 * 4];
        }
        if (t < 64) {
            const int b = t;
            const size_t base = (size_t)(b * 8 + hh) * 4;
            esum_l[b] = esum_pt[base] + esum_pt[base + 1] + esum_pt[base + 2] + esum_pt[base + 3];
            msum_l[b] = msum_pt[base] + msum_pt[base + 1] + msum_pt[base + 2] + msum_pt[base + 3];
        }
        __syncthreads();
        // pool2[b][o] (4096 elems)
#pragma unroll
        for (int u = 0; u < 16; ++u) {
            const int f = t + 256 * u;
            const int b = f >> 6, o = f & 63;
            const size_t base = ((size_t)(b * 8 + hh) * 4) * 64 + o;
            pool2_l[b][o] = (pool_pt[base] + pool_pt[base + 64]
                           + pool_pt[base + 128] + pool_pt[base + 192]) / msum_l[b];
        }
        __syncthreads();
        // att rows -> xl (8192 elems)
#pragma unroll
        for (int u = 0; u < 32; ++u) {
            const int f = t + 256 * u;
            const int b = f >> 7, d = f & 127;
            const size_t base = ((size_t)(b * 8 + hh) * 4) * 128 + d;
            const float av = av_pt[base] + av_pt[base + 128]
                           + av_pt[base + 256] + av_pt[base + 384];
            float ac = bc[hh * 128 + d];
#pragma unroll 8
            for (int o = 0; o < 64; ++o)
                ac = fmaf(pool2_l[b][o], wc_l[o][d], ac);
            const float sig = 1.f / (1.f + expf(-ac));
            xl[b][d] = (av / esum_l[b]) * sig * v1[b * 1024 + hh * 128 + d];
        }
        __syncthreads();              // xl ready; wc_l (wl) free to overwrite
    } else {
        const int kbase = kq * 128;
#pragma unroll
        for (int u = 0; u < 8; ++u) {
            const int f = t + 256 * u;
            const int r = f >> 5, k4 = f & 31;
            *(float4*)&xl[r][k4 * 4] = *(const float4*)&h[r * 1024 + kbase + k4 * 4];
        }
    }

    // stage Wt tile (128x64)
#pragma unroll
    for (int u = 0; u < 8; ++u) {
        const int f = t + 256 * u;
        const int row = f >> 4, c4 = f & 15;
        *(float4*)&wl[row][c4 * 4] =
            *(const float4*)&Wt[(size_t)(kq * 128 + row) * 1024 + cc + c4 * 4];
    }
    __syncthreads();

    const int r0 = (t >> 4) * 4;
    const int c0 = (t & 15) * 4;
    float acc[4][4];
#pragma unroll
    for (int i = 0; i < 4; ++i)
#pragma unroll
        for (int j = 0; j < 4; ++j) acc[i][j] = 0.f;

#pragma unroll 4
    for (int k = 0; k < 128; ++k) {
        const float4 w4 = *(const float4*)&wl[k][c0];
        const float h0 = xl[r0][k], h1 = xl[r0 + 1][k];
        const float h2 = xl[r0 + 2][k], h3 = xl[r0 + 3][k];
        acc[0][0] = fmaf(h0, w4.x, acc[0][0]); acc[0][1] = fmaf(h0, w4.y, acc[0][1]);
        acc[0][2] = fmaf(h0, w4.z, acc[0][2]); acc[0][3] = fmaf(h0, w4.w, acc[0][3]);
        acc[1][0] = fmaf(h1, w4.x, acc[1][0]); acc[1][1] = fmaf(h1, w4.y, acc[1][1]);
        acc[1][2] = fmaf(h1, w4.z, acc[1][2]); acc[1][3] = fmaf(h1, w4.w, acc[1][3]);
        acc[2][0] = fmaf(h2, w4.x, acc[2][0]); acc[2][1] = fmaf(h2, w4.y, acc[2][1]);
        acc[2][2] = fmaf(h2, w4.z, acc[2][2]); acc[2][3] = fmaf(h2, w4.w, acc[2][3]);
        acc[3][0] = fmaf(h3, w4.x, acc[3][0]); acc[3][1] = fmaf(h3, w4.y, acc[3][1]);
        acc[3][2] = fmaf(h3, w4.z, acc[3][2]); acc[3][3] = fmaf(h3, w4.w, acc[3][3]);
    }

#pragma unroll
    for (int i = 0; i < 4; ++i) {
        float4 v = {acc[i][0], acc[i][1], acc[i][2], acc[i][3]};
        *(float4*)&part[(size_t)kq * 65536 + (r0 + i) * 1024 + cc + c0] = v;
    }
}

// ---------------------------------------------------------------------------
// C2: sum 16 partials + bt, LayerNorm (ddof=0). grid 64 rows, block 256
// ---------------------------------------------------------------------------
__global__ __launch_bounds__(256) void c2_ln(
    const float* __restrict__ part, const float* __restrict__ bt,
    const float* __restrict__ lnw, const float* __restrict__ lnb,
    float* __restrict__ out)
{
    const int t = threadIdx.x;
    const int row = blockIdx.x;
    const int w = t >> 6, lane = t & 63;
    __shared__ float red[4];

    float4 v = *(const float4*)&bt[t * 4];
#pragma unroll
    for (int qd = 0; qd < 16; ++qd) {
        const float4 p = *(const float4*)&part[(size_t)qd * 65536 + row * 1024 + t * 4];
        v.x += p.x; v.y += p.y; v.z += p.z; v.w += p.w;
    }
    float s = v.x + v.y + v.z + v.w;
#pragma unroll
    for (int m = 32; m >= 1; m >>= 1) s += __shfl_xor(s, m);
    if (lane == 0) red[w] = s;
    __syncthreads();
    const float mean = (red[0] + red[1] + red[2] + red[3]) * (1.f / 1024.f);
    __syncthreads();
    const float d0 = v.x - mean, d1 = v.y - mean, d2 = v.z - mean, d3 = v.w - mean;
    float ss = d0 * d0 + d1 * d1 + d2 * d2 + d3 * d3;
#pragma unroll
    for (int m = 32; m >= 1; m >>= 1) ss += __shfl_xor(ss, m);
    if (lane == 0) red[w] = ss;
    __syncthreads();
    const float var = (red[0] + red[1] + red[2] + red[3]) * (1.f / 1024.f);
    const float inv = rsqrtf(var + 1e-5f);
    const float4 w4 = *(const float4*)&lnw[t * 4];
    const float4 b4 = *(const float4*)&lnb[t * 4];
    float4 y;
    y.x = d0 * inv * w4.x + b4.x;
    y.y = d1 * inv * w4.y + b4.y;
    y.z = d2 * inv * w4.z + b4.z;
    y.w = d3 * inv * w4.w + b4.w;
    *(float4*)&out[row * 1024 + t * 4] = y;
}

// ---------------------------------------------------------------------------
extern "C" void kernel_launch(void* const* d_in, const int* in_sizes, int n_in,
                              void* d_out, int out_size, void* d_ws, size_t ws_size,
                              hipStream_t stream)
{
    const float* h_state  = (const float*)d_in[0];
    // d_in[1] = att_feats: UNUSED by the reference — never read
    const float* att_mask = (const float*)d_in[2];
    const float* pat      = (const float*)d_in[3];
    const float* Wq       = (const float*)d_in[4];
    const float* bq       = (const float*)d_in[5];
    const float* gnw_q    = (const float*)d_in[6];
    const float* gnb_q    = (const float*)d_in[7];
    const float* Wv1      = (const float*)d_in[8];
    const float* bv1      = (const float*)d_in[9];
    const float* gnw_v1   = (const float*)d_in[10];
    const float* gnb_v1   = (const float*)d_in[11];
    const float* Wb       = (const float*)d_in[12];
    const float* bb       = (const float*)d_in[13];
    const float* Ws       = (const float*)d_in[14];
    const float* bs       = (const float*)d_in[15];
    const float* Wc       = (const float*)d_in[16];
    const float* bc       = (const float*)d_in[17];
    const float* Wt       = (const float*)d_in[18];
    const float* bt       = (const float*)d_in[19];
    const float* lnw      = (const float*)d_in[20];
    const float* lnb      = (const float*)d_in[21];
    float* out = (float*)d_out;

    float* ws      = (float*)d_ws;
    float* v1buf   = ws;                     // 64K floats
    float* parts   = ws + 65536;             // 16 x 64K = 1M floats
    short* wbq_g   = (short*)(ws + 1114112); // 512*8192 bf16 = 8 MB (2M float slots)
    float* pool_pt = ws + 3211264;           // 2048*64
    float* esum_pt = ws + 3342336;           // 2048
    float* msum_pt = ws + 3344384;           // 2048
    float* av_pt   = ws + 3346432;           // 2048*128

    a1_tile<<<256, 256, 0, stream>>>(h_state, Wq, Wv1, parts);
    a2b0<<<512, 256, 0, stream>>>(parts, bq, bv1, gnw_q, gnb_q, gnw_v1, gnb_v1,
                                  Wb, v1buf, wbq_g);
    b_fused<<<2048, 256, 0, stream>>>(pat, att_mask, wbq_g, bb, Ws, bs,
                                      pool_pt, esum_pt, msum_pt, av_pt);
    c1_fused<<<256, 256, 0, stream>>>(h_state, Wt, pool_pt, esum_pt, msum_pt,
                                      av_pt, Wc, bc, v1buf, parts);
    c2_ln<<<64, 256, 0, stream>>>(parts, bt, lnw, lnb, out);
}

// Round 11
// 160.695 us; speedup vs baseline: 1.0720x; 1.0720x over previous
//
#include <hip/hip_runtime.h>
#include <hip/hip_bf16.h>
#include <cmath>

#define NB 64
#define NM 1024
#define NE 1024
#define NH 8
#define NHD 128
#define NMID 64
#define CELU_ALPHA 1.3f

typedef __attribute__((ext_vector_type(8))) short bf16x8;
typedef __attribute__((ext_vector_type(4))) float f32x4;

__device__ __forceinline__ float celuf(float x) {
    return x > 0.f ? x : CELU_ALPHA * expm1f(x / CELU_ALPHA);
}

__device__ __forceinline__ short f2bf(float x) {
    __hip_bfloat16 b = __float2bfloat16(x);
    return *reinterpret_cast<short*>(&b);
}

// ---------------------------------------------------------------------------
// A1: LDS-tiled fp32 GEMM partials for q/v1 pre-activations.
// grid 256 = mat(2) x kq(8) x cc(16 of 64 cols), block 256.
// ---------------------------------------------------------------------------
__global__ __launch_bounds__(256) void a1_tile(
    const float* __restrict__ h, const float* __restrict__ Wq,
    const float* __restrict__ Wv1, float* __restrict__ partA)
{
    const int t = threadIdx.x;
    const int mat = blockIdx.x >> 7;
    const int kq = (blockIdx.x >> 4) & 7;
    const int cc = (blockIdx.x & 15) * 64;
    const int kbase = kq * 128;
    const float* __restrict__ W = mat ? Wv1 : Wq;

    __shared__ float wl[128][64];
    __shared__ float hl[64][132];

#pragma unroll
    for (int u = 0; u < 8; ++u) {            // stage W tile: 128x64
        const int f = t + 256 * u;
        const int row = f >> 4, c4 = f & 15;
        *(float4*)&wl[row][c4 * 4] =
            *(const float4*)&W[(size_t)(kbase + row) * 1024 + cc + c4 * 4];
    }
#pragma unroll
    for (int u = 0; u < 8; ++u) {            // stage h tile: 64x128
        const int f = t + 256 * u;
        const int r = f >> 5, k4 = f & 31;
        *(float4*)&hl[r][k4 * 4] = *(const float4*)&h[r * 1024 + kbase + k4 * 4];
    }
    __syncthreads();

    const int r0 = (t >> 4) * 4;
    const int c0 = (t & 15) * 4;
    float acc[4][4];
#pragma unroll
    for (int i = 0; i < 4; ++i)
#pragma unroll
        for (int j = 0; j < 4; ++j) acc[i][j] = 0.f;

#pragma unroll 4
    for (int k = 0; k < 128; ++k) {
        const float4 w4 = *(const float4*)&wl[k][c0];
        const float h0 = hl[r0][k], h1 = hl[r0 + 1][k];
        const float h2 = hl[r0 + 2][k], h3 = hl[r0 + 3][k];
        acc[0][0] = fmaf(h0, w4.x, acc[0][0]); acc[0][1] = fmaf(h0, w4.y, acc[0][1]);
        acc[0][2] = fmaf(h0, w4.z, acc[0][2]); acc[0][3] = fmaf(h0, w4.w, acc[0][3]);
        acc[1][0] = fmaf(h1, w4.x, acc[1][0]); acc[1][1] = fmaf(h1, w4.y, acc[1][1]);
        acc[1][2] = fmaf(h1, w4.z, acc[1][2]); acc[1][3] = fmaf(h1, w4.w, acc[1][3]);
        acc[2][0] = fmaf(h2, w4.x, acc[2][0]); acc[2][1] = fmaf(h2, w4.y, acc[2][1]);
        acc[2][2] = fmaf(h2, w4.z, acc[2][2]); acc[2][3] = fmaf(h2, w4.w, acc[2][3]);
        acc[3][0] = fmaf(h3, w4.x, acc[3][0]); acc[3][1] = fmaf(h3, w4.y, acc[3][1]);
        acc[3][2] = fmaf(h3, w4.z, acc[3][2]); acc[3][3] = fmaf(h3, w4.w, acc[3][3]);
    }

    float* __restrict__ out = partA + (size_t)(mat * 8 + kq) * 65536;
#pragma unroll
    for (int i = 0; i < 4; ++i) {
        float4 v = {acc[i][0], acc[i][1], acc[i][2], acc[i][3]};
        *(float4*)&out[(r0 + i) * 1024 + cc + c0] = v;
    }
}

// ---------------------------------------------------------------------------
// A2B0: per-(b,h): sum partials + bias + CELU + groupnorm (ddof=1) for q & v1,
// write v1buf, build wbq_g (bf16, fragment-ready). grid 512 = (b,h).
// Wb staged coalesced in LDS.
// ---------------------------------------------------------------------------
__global__ __launch_bounds__(256) void a2b0(
    const float* __restrict__ partA,
    const float* __restrict__ bq, const float* __restrict__ bv1,
    const float* __restrict__ gnw_q, const float* __restrict__ gnb_q,
    const float* __restrict__ gnw_v, const float* __restrict__ gnb_v,
    const float* __restrict__ Wb,
    float* __restrict__ v1buf, short* __restrict__ wbq_g)
{
    const int bid = blockIdx.x;
    const int b = bid >> 3, hh = bid & 7;
    const int t = threadIdx.x;
    const int mat = t >> 7;          // 0 = q, 1 = v1
    const int c = t & 127;
    const int ch = hh * 128 + c;
    const int w = t >> 6, lane = t & 63;

    __shared__ float q_lds[128];
    __shared__ float red[4][2];
    __shared__ float wb_l[128][68];  // Wb[hh] staged [i][o], pad 68

    // stage Wb[hh] coalesced: 2048 float4s
#pragma unroll
    for (int u = 0; u < 8; ++u) {
        const int f = t + 256 * u;
        const int i = f >> 4, o4 = f & 15;
        *(float4*)&wb_l[i][o4 * 4] = *(const float4*)&Wb[hh * 8192 + i * 64 + o4 * 4];
    }

    float x = mat ? bv1[ch] : bq[ch];
#pragma unroll
    for (int kq = 0; kq < 8; ++kq)
        x += partA[(size_t)(mat * 8 + kq) * 65536 + b * 1024 + ch];
    x = celuf(x);

    float s = x, s2 = x * x;
#pragma unroll
    for (int m = 32; m >= 1; m >>= 1) {
        s += __shfl_xor(s, m);
        s2 += __shfl_xor(s2, m);
    }
    if (lane == 0) { red[w][0] = s; red[w][1] = s2; }
    __syncthreads();                  // red + wb_l ready
    const float S  = red[mat * 2][0] + red[mat * 2 + 1][0];
    const float S2 = red[mat * 2][1] + red[mat * 2 + 1][1];
    const float mean = S * (1.f / 128.f);
    const float var = (S2 - 128.f * mean * mean) * (1.f / 127.f);
    const float inv = rsqrtf(var + 1e-5f);
    const float gw = mat ? gnw_v[ch] : gnw_q[ch];
    const float gb = mat ? gnb_v[ch] : gnb_q[ch];
    const float y = (x - mean) * inv * gw + gb;
    if (mat == 0) q_lds[c] = y;
    else v1buf[b * 1024 + ch] = y;
    __syncthreads();

    // build wbq_g[bid][o][i]: thread owns o = t&63, i-block (t>>6)*32
    const int o = t & 63;
    const int i0 = (t >> 6) * 32;
    union { short sv[32]; uint4 q4[4]; } u;
#pragma unroll 8
    for (int v = 0; v < 32; ++v) {
        const int i = i0 + v;
        u.sv[v] = f2bf(q_lds[i] * wb_l[i][o]);
    }
    uint4* dst = (uint4*)&wbq_g[(size_t)bid * 8192 + o * 128 + i0];
#pragma unroll
    for (int r = 0; r < 4; ++r) dst[r] = u.q4[r];
}

// ---------------------------------------------------------------------------
// B: fused flash-style streaming over K and V halves. grid 2048 = (b,h,chunk)
// B-frags in REGISTERS (zero in-loop LDS traffic); V loads inline unroll 8;
// no forced occupancy bound — aims ~150-165 VGPR -> 3 waves/SIMD.
// ---------------------------------------------------------------------------
__global__ __launch_bounds__(256) void b_fused(
    const float* __restrict__ pat, const float* __restrict__ mask,
    const short* __restrict__ wbq_g,
    const float* __restrict__ bb, const float* __restrict__ Ws,
    const float* __restrict__ bs,
    float* __restrict__ pool_pt, float* __restrict__ esum_pt,
    float* __restrict__ av_pt)
{
    const int t = threadIdx.x;
    const int bid = blockIdx.x;
    const int b = bid >> 5;
    const int h = (bid >> 2) & 7;
    const int chunk = bid & 3;
    const int w = t >> 6;
    const int lane = t & 63;
    const int ln15 = lane & 15;
    const int lg = lane >> 4;
    const int dg = lane & 31;
    const int rwg = lane >> 5;

    __shared__ float mask_lds[256];
    __shared__ float e_lds[4][16];
    __shared__ float att_red[4][128];
    __shared__ float pool_red[4][64];
    __shared__ float esum_red[4];

    mask_lds[t] = mask[b * 1024 + chunk * 256 + t];

    // B-fragments direct from precomputed wbq (coalesced 16B loads)
    const short* __restrict__ wb = wbq_g + (size_t)(bid >> 2) * 8192;
    bf16x8 bfr[4][4];
#pragma unroll
    for (int nt = 0; nt < 4; ++nt)
#pragma unroll
        for (int ks = 0; ks < 4; ++ks)
            bfr[nt][ks] = *(const bf16x8*)&wb[(nt * 16 + ln15) * 128 + ks * 32 + lg * 8];

    float wsr[4], bbr[4];
#pragma unroll
    for (int nt = 0; nt < 4; ++nt) {
        wsr[nt] = Ws[h * 64 + nt * 16 + ln15];
        bbr[nt] = bb[h * 64 + nt * 16 + ln15];
    }
    const float bsh = bs[h];
    float pool_part[4] = {0.f, 0.f, 0.f, 0.f};
    float esum_part = 0.f;
    float4 a4 = {0.f, 0.f, 0.f, 0.f};

    const float* __restrict__ patk = pat + (size_t)b * NM * 2048 + h * 128;
    const float* __restrict__ patv = patk + 1024;

    __syncthreads();   // mask_lds ready

    for (int it = 0; it < 4; ++it) {
        const int ml0 = (w * 4 + it) * 16;       // row within chunk
        const int m0 = chunk * 256 + ml0;        // global row

        // ---- A loads for this tile (8 x float4 in flight) ----
        const float* __restrict__ rowp = patk + (size_t)(m0 + ln15) * 2048 + lg * 8;
        float4 ax[4], ay[4];
#pragma unroll
        for (int ks = 0; ks < 4; ++ks) {
            ax[ks] = *(const float4*)(rowp + ks * 32);
            ay[ks] = *(const float4*)(rowp + ks * 32 + 4);
        }

        // ---- cvt A to bf16 fragments ----
        bf16x8 af[4];
#pragma unroll
        for (int ks = 0; ks < 4; ++ks) {
            union { bf16x8 v; short s[8]; } u8;
            u8.s[0] = f2bf(ax[ks].x); u8.s[1] = f2bf(ax[ks].y);
            u8.s[2] = f2bf(ax[ks].z); u8.s[3] = f2bf(ax[ks].w);
            u8.s[4] = f2bf(ay[ks].x); u8.s[5] = f2bf(ay[ks].y);
            u8.s[6] = f2bf(ay[ks].z); u8.s[7] = f2bf(ay[ks].w);
            af[ks] = u8.v;
        }

        // ---- MFMA (all operands in registers) ----
        f32x4 acc[4];
#pragma unroll
        for (int nt = 0; nt < 4; ++nt) acc[nt] = (f32x4){0.f, 0.f, 0.f, 0.f};
#pragma unroll
        for (int ks = 0; ks < 4; ++ks)
#pragma unroll
            for (int nt = 0; nt < 4; ++nt)
                acc[nt] = __builtin_amdgcn_mfma_f32_16x16x32_bf16(af[ks], bfr[nt][ks], acc[nt], 0, 0, 0);

        // ---- epilogue: bias+relu, score dot Ws, pool, e = exp ----
#pragma unroll
        for (int j = 0; j < 4; ++j) {
            const int ml = ml0 + lg * 4 + j;
            const float mk = mask_lds[ml];
            float sp = 0.f;
#pragma unroll
            for (int nt = 0; nt < 4; ++nt) {
                float a = acc[nt][j] + bbr[nt];
                a = fmaxf(a, 0.f);
                sp = fmaf(a, wsr[nt], sp);
                pool_part[nt] = fmaf(a, mk, pool_part[nt]);
            }
            sp += __shfl_xor(sp, 1);
            sp += __shfl_xor(sp, 2);
            sp += __shfl_xor(sp, 4);
            sp += __shfl_xor(sp, 8);
            if (ln15 == 0) {
                const float e = (mk == 0.f) ? 0.f : expf(sp + bsh);
                e_lds[w][lg * 4 + j] = e;    // wave-local (same-wave DS order)
                esum_part += e;
            }
        }

        // ---- V accumulate: inline loads, full unroll (8 in flight) ----
        const float* __restrict__ vrow = patv + (size_t)(m0 + rwg) * 2048 + dg * 4;
#pragma unroll 8
        for (int r = 0; r < 8; ++r) {
            const float4 v = *(const float4*)(vrow + (size_t)(2 * r) * 2048);
            const float e = e_lds[w][rwg + 2 * r];
            a4.x = fmaf(e, v.x, a4.x);
            a4.y = fmaf(e, v.y, a4.y);
            a4.z = fmaf(e, v.z, a4.z);
            a4.w = fmaf(e, v.w, a4.w);
        }
    }

    // ---- reductions ----
    a4.x += __shfl_xor(a4.x, 32);
    a4.y += __shfl_xor(a4.y, 32);
    a4.z += __shfl_xor(a4.z, 32);
    a4.w += __shfl_xor(a4.w, 32);
    if (lane < 32) *(float4*)&att_red[w][dg * 4] = a4;

#pragma unroll
    for (int nt = 0; nt < 4; ++nt) {
        float p = pool_part[nt];
        p += __shfl_xor(p, 16);
        p += __shfl_xor(p, 32);
        if (lane < 16) pool_red[w][nt * 16 + lane] = p;
    }

#pragma unroll
    for (int m = 32; m >= 1; m >>= 1) esum_part += __shfl_xor(esum_part, m);
    if (lane == 0) esum_red[w] = esum_part;
    __syncthreads();

    if (t < 128)
        av_pt[(size_t)bid * 128 + t] =
            att_red[0][t] + att_red[1][t] + att_red[2][t] + att_red[3][t];
    else if (t < 192)
        pool_pt[(size_t)bid * 64 + (t - 128)] =
            pool_red[0][t - 128] + pool_red[1][t - 128] + pool_red[2][t - 128] + pool_red[3][t - 128];
    else if (t == 192)
        esum_pt[bid] = esum_red[0] + esum_red[1] + esum_red[2] + esum_red[3];
}

// ---------------------------------------------------------------------------
// B5: finalize. grid 512 = (b,h), block 256.
// ---------------------------------------------------------------------------
__global__ __launch_bounds__(256) void b5_final(
    const float* __restrict__ pool_pt, const float* __restrict__ esum_pt,
    const float* __restrict__ av_pt, const float* __restrict__ mask,
    const float* __restrict__ Wc, const float* __restrict__ bc,
    const float* __restrict__ v1, float* __restrict__ att_out)
{
    const int t = threadIdx.x;
    const int bid = blockIdx.x;            // b*8 + h
    const int b = bid >> 3;
    const int h = bid & 7;
    const int w = t >> 6, lane = t & 63;

    __shared__ float red4[4];
    __shared__ float pool2[64];

    const float4 mk4 = *(const float4*)&mask[b * 1024 + t * 4];
    float msp = mk4.x + mk4.y + mk4.z + mk4.w;
#pragma unroll
    for (int m = 32; m >= 1; m >>= 1) msp += __shfl_xor(msp, m);
    if (lane == 0) red4[w] = msp;
    __syncthreads();
    const float msum = red4[0] + red4[1] + red4[2] + red4[3];

    if (t < 64) {
        const float pp = pool_pt[(size_t)(bid * 4) * 64 + t] + pool_pt[(size_t)(bid * 4 + 1) * 64 + t]
                       + pool_pt[(size_t)(bid * 4 + 2) * 64 + t] + pool_pt[(size_t)(bid * 4 + 3) * 64 + t];
        pool2[t] = pp / msum;
    }
    __syncthreads();

    if (t < 128) {
        const int d = t;
        const float av = av_pt[(size_t)(bid * 4) * 128 + d] + av_pt[(size_t)(bid * 4 + 1) * 128 + d]
                       + av_pt[(size_t)(bid * 4 + 2) * 128 + d] + av_pt[(size_t)(bid * 4 + 3) * 128 + d];
        const float esum = esum_pt[bid * 4] + esum_pt[bid * 4 + 1]
                         + esum_pt[bid * 4 + 2] + esum_pt[bid * 4 + 3];
        const float att = av / esum;
        float ac = bc[h * 128 + d];
#pragma unroll 8
        for (int o = 0; o < 64; ++o)
            ac = fmaf(pool2[o], Wc[h * 8192 + o * 128 + d], ac);
        const float sig = 1.f / (1.f + expf(-ac));
        att_out[b * 1024 + h * 128 + d] = att * sig * v1[b * 1024 + h * 128 + d];
    }
}

// ---------------------------------------------------------------------------
// C1: LDS-tiled fp32 GEMM partials for out = [h | att] @ Wt.
// grid 256 = kq(16) x cc(16 of 64 cols), block 256.
// ---------------------------------------------------------------------------
__global__ __launch_bounds__(256) void c1_tile(
    const float* __restrict__ h, const float* __restrict__ att,
    const float* __restrict__ Wt, float* __restrict__ part)
{
    const int t = threadIdx.x;
    const int kq = blockIdx.x >> 4;
    const int cc = (blockIdx.x & 15) * 64;
    const float* __restrict__ x = (kq < 8) ? h : att;
    const int kbase = (kq & 7) * 128;

    __shared__ float wl[128][64];
    __shared__ float hl[64][132];

#pragma unroll
    for (int u = 0; u < 8; ++u) {
        const int f = t + 256 * u;
        const int row = f >> 4, c4 = f & 15;
        *(float4*)&wl[row][c4 * 4] =
            *(const float4*)&Wt[(size_t)(kq * 128 + row) * 1024 + cc + c4 * 4];
    }
#pragma unroll
    for (int u = 0; u < 8; ++u) {
        const int f = t + 256 * u;
        const int r = f >> 5, k4 = f & 31;
        *(float4*)&hl[r][k4 * 4] = *(const float4*)&x[r * 1024 + kbase + k4 * 4];
    }
    __syncthreads();

    const int r0 = (t >> 4) * 4;
    const int c0 = (t & 15) * 4;
    float acc[4][4];
#pragma unroll
    for (int i = 0; i < 4; ++i)
#pragma unroll
        for (int j = 0; j < 4; ++j) acc[i][j] = 0.f;

#pragma unroll 4
    for (int k = 0; k < 128; ++k) {
        const float4 w4 = *(const float4*)&wl[k][c0];
        const float h0 = hl[r0][k], h1 = hl[r0 + 1][k];
        const float h2 = hl[r0 + 2][k], h3 = hl[r0 + 3][k];
        acc[0][0] = fmaf(h0, w4.x, acc[0][0]); acc[0][1] = fmaf(h0, w4.y, acc[0][1]);
        acc[0][2] = fmaf(h0, w4.z, acc[0][2]); acc[0][3] = fmaf(h0, w4.w, acc[0][3]);
        acc[1][0] = fmaf(h1, w4.x, acc[1][0]); acc[1][1] = fmaf(h1, w4.y, acc[1][1]);
        acc[1][2] = fmaf(h1, w4.z, acc[1][2]); acc[1][3] = fmaf(h1, w4.w, acc[1][3]);
        acc[2][0] = fmaf(h2, w4.x, acc[2][0]); acc[2][1] = fmaf(h2, w4.y, acc[2][1]);
        acc[2][2] = fmaf(h2, w4.z, acc[2][2]); acc[2][3] = fmaf(h2, w4.w, acc[2][3]);
        acc[3][0] = fmaf(h3, w4.x, acc[3][0]); acc[3][1] = fmaf(h3, w4.y, acc[3][1]);
        acc[3][2] = fmaf(h3, w4.z, acc[3][2]); acc[3][3] = fmaf(h3, w4.w, acc[3][3]);
    }

#pragma unroll
    for (int i = 0; i < 4; ++i) {
        float4 v = {acc[i][0], acc[i][1], acc[i][2], acc[i][3]};
        *(float4*)&part[(size_t)kq * 65536 + (r0 + i) * 1024 + cc + c0] = v;
    }
}

// ---------------------------------------------------------------------------
// C2: sum 16 partials + bt, LayerNorm (ddof=0). grid 64 rows, block 256
// ---------------------------------------------------------------------------
__global__ __launch_bounds__(256) void c2_ln(
    const float* __restrict__ part, const float* __restrict__ bt,
    const float* __restrict__ lnw, const float* __restrict__ lnb,
    float* __restrict__ out)
{
    const int t = threadIdx.x;
    const int row = blockIdx.x;
    const int w = t >> 6, lane = t & 63;
    __shared__ float red[4];

    float4 v = *(const float4*)&bt[t * 4];
#pragma unroll
    for (int qd = 0; qd < 16; ++qd) {
        const float4 p = *(const float4*)&part[(size_t)qd * 65536 + row * 1024 + t * 4];
        v.x += p.x; v.y += p.y; v.z += p.z; v.w += p.w;
    }
    float s = v.x + v.y + v.z + v.w;
#pragma unroll
    for (int m = 32; m >= 1; m >>= 1) s += __shfl_xor(s, m);
    if (lane == 0) red[w] = s;
    __syncthreads();
    const float mean = (red[0] + red[1] + red[2] + red[3]) * (1.f / 1024.f);
    __syncthreads();
    const float d0 = v.x - mean, d1 = v.y - mean, d2 = v.z - mean, d3 = v.w - mean;
    float ss = d0 * d0 + d1 * d1 + d2 * d2 + d3 * d3;
#pragma unroll
    for (int m = 32; m >= 1; m >>= 1) ss += __shfl_xor(ss, m);
    if (lane == 0) red[w] = ss;
    __syncthreads();
    const float var = (red[0] + red[1] + red[2] + red[3]) * (1.f / 1024.f);
    const float inv = rsqrtf(var + 1e-5f);
    const float4 w4 = *(const float4*)&lnw[t * 4];
    const float4 b4 = *(const float4*)&lnb[t * 4];
    float4 y;
    y.x = d0 * inv * w4.x + b4.x;
    y.y = d1 * inv * w4.y + b4.y;
    y.z = d2 * inv * w4.z + b4.z;
    y.w = d3 * inv * w4.w + b4.w;
    *(float4*)&out[row * 1024 + t * 4] = y;
}

// ---------------------------------------------------------------------------
extern "C" void kernel_launch(void* const* d_in, const int* in_sizes, int n_in,
                              void* d_out, int out_size, void* d_ws, size_t ws_size,
                              hipStream_t stream)
{
    const float* h_state  = (const float*)d_in[0];
    // d_in[1] = att_feats: UNUSED by the reference — never read
    const float* att_mask = (const float*)d_in[2];
    const float* pat      = (const float*)d_in[3];
    const float* Wq       = (const float*)d_in[4];
    const float* bq       = (const float*)d_in[5];
    const float* gnw_q    = (const float*)d_in[6];
    const float* gnb_q    = (const float*)d_in[7];
    const float* Wv1      = (const float*)d_in[8];
    const float* bv1      = (const float*)d_in[9];
    const float* gnw_v1   = (const float*)d_in[10];
    const float* gnb_v1   = (const float*)d_in[11];
    const float* Wb       = (const float*)d_in[12];
    const float* bb       = (const float*)d_in[13];
    const float* Ws       = (const float*)d_in[14];
    const float* bs       = (const float*)d_in[15];
    const float* Wc       = (const float*)d_in[16];
    const float* bc       = (const float*)d_in[17];
    const float* Wt       = (const float*)d_in[18];
    const float* bt       = (const float*)d_in[19];
    const float* lnw      = (const float*)d_in[20];
    const float* lnb      = (const float*)d_in[21];
    float* out = (float*)d_out;

    float* ws      = (float*)d_ws;
    float* v1buf   = ws;                     // 64K floats
    float* attb    = ws + 65536;             // 64K
    float* parts   = ws + 131072;            // 16 x 64K = 1M floats
    short* wbq_g   = (short*)(ws + 1179648); // 512*8192 bf16 = 8 MB
    float* pool_pt = ws + 3276800;           // 2048*64
    float* esum_pt = ws + 3407872;           // 2048
    float* av_pt   = ws + 3409920;           // 2048*128

    a1_tile<<<256, 256, 0, stream>>>(h_state, Wq, Wv1, parts);
    a2b0<<<512, 256, 0, stream>>>(parts, bq, bv1, gnw_q, gnb_q, gnw_v1, gnb_v1,
                                  Wb, v1buf, wbq_g);
    b_fused<<<2048, 256, 0, stream>>>(pat, att_mask, wbq_g, bb, Ws, bs,
                                      pool_pt, esum_pt, av_pt);
    b5_final<<<512, 256, 0, stream>>>(pool_pt, esum_pt, av_pt, att_mask,
                                      Wc, bc, v1buf, attb);
    c1_tile<<<256, 256, 0, stream>>>(h_state, attb, Wt, parts);
    c2_ln<<<64, 256, 0, stream>>>(parts, bt, lnw, lnb, out);
}